// Round 1
// baseline (172.197 us; speedup 1.0000x reference)
//
#include <hip/hip_runtime.h>
#include <math.h>

#define N_NODES 10000
#define BATCH   32
#define F_IN    5
#define HID     128
#define LN_EPS  1e-5f
#define CHUNK   500
#define NB_PER_BATCH (N_NODES / CHUNK)   // 20
#define NBLK (BATCH * NB_PER_BATCH)      // 640

// Kernel 1: fused stencil-GCN + ReLU + LayerNorm + per-block pooled partial sum.
// One wave per node; lane owns features (lane, lane+64).
__global__ __launch_bounds__(256) void gcn_ln_pool_kernel(
    const float* __restrict__ state, const float* __restrict__ action,
    const float* __restrict__ conv_w, const float* __restrict__ conv_b,
    const float* __restrict__ ln_g, const float* __restrict__ ln_b,
    float* __restrict__ partial)
{
    __shared__ float s_sa[(CHUNK + 2) * F_IN];   // sa for nodes [n0-1, n0+CHUNK]
    __shared__ float s_red[4][HID];

    const int b     = blockIdx.x / NB_PER_BATCH;
    const int chunk = blockIdx.x % NB_PER_BATCH;
    const int n0    = chunk * CHUNK;
    const int t     = threadIdx.x;

    // Stage sa (= flat [state_row | action_row] re-index) coalesced into LDS.
    const int base = (n0 - 1) * F_IN;            // concat index of first staged element
    for (int e = t; e < (CHUNK + 2) * F_IN; e += 256) {
        int g = base + e;
        float v = 0.f;
        if (g >= 0 && g < N_NODES * F_IN) {
            v = (g < N_NODES * 4) ? state[b * (N_NODES * 4) + g]
                                  : action[b * N_NODES + (g - N_NODES * 4)];
        }
        s_sa[e] = v;
    }

    const int wave = t >> 6;
    const int lane = t & 63;
    const int f0 = lane, f1 = lane + 64;

    // Per-lane parameter registers (fixed features for whole kernel).
    float w0[F_IN], w1[F_IN];
#pragma unroll
    for (int k = 0; k < F_IN; ++k) {
        w0[k] = conv_w[k * HID + f0];
        w1[k] = conv_w[k * HID + f1];
    }
    const float cb0 = conv_b[f0], cb1 = conv_b[f1];
    const float g0  = ln_g[f0],   g1  = ln_g[f1];
    const float be0 = ln_b[f0],   be1 = ln_b[f1];

    __syncthreads();

    float acc0 = 0.f, acc1 = 0.f;

    for (int n = n0 + wave; n < n0 + CHUNK; n += 4) {
        // GCN symmetric-norm stencil coefficients (deg: 2 at ends, 3 interior).
        const float degC = (n == 0 || n == N_NODES - 1) ? 2.f : 3.f;
        const float wC = 1.f / degC;
        float wL = 0.f, wR = 0.f;
        if (n > 0)           { const float degL = (n == 1) ? 2.f : 3.f;           wL = rsqrtf(degL * degC); }
        if (n < N_NODES - 1) { const float degR = (n == N_NODES - 2) ? 2.f : 3.f; wR = rsqrtf(degR * degC); }

        const int li = (n - n0 + 1) * F_IN;      // local LDS index of node n
        float v0 = cb0, v1 = cb1;
#pragma unroll
        for (int k = 0; k < F_IN; ++k) {
            // Aggregate 5-dim input first (linearity of GCN), then transform.
            const float sagg = wL * s_sa[li - F_IN + k] + wC * s_sa[li + k] + wR * s_sa[li + F_IN + k];
            v0 = fmaf(sagg, w0[k], v0);
            v1 = fmaf(sagg, w1[k], v1);
        }
        v0 = fmaxf(v0, 0.f); v1 = fmaxf(v1, 0.f);

        // LayerNorm over 128 features: in-wave butterfly for sum & sumsq.
        float s = v0 + v1, sq = v0 * v0 + v1 * v1;
#pragma unroll
        for (int m = 1; m < 64; m <<= 1) {
            s  += __shfl_xor(s, m);
            sq += __shfl_xor(sq, m);
        }
        const float mean = s * (1.f / 128.f);
        const float var  = sq * (1.f / 128.f) - mean * mean;
        const float r    = rsqrtf(var + LN_EPS);
        acc0 += (v0 - mean) * r * g0 + be0;
        acc1 += (v1 - mean) * r * g1 + be1;
    }

    // Block reduction of pooled partials (deterministic, no atomics).
    s_red[wave][f0] = acc0;
    s_red[wave][f1] = acc1;
    __syncthreads();
    if (t < HID) {
        const float p = s_red[0][t] + s_red[1][t] + s_red[2][t] + s_red[3][t];
        partial[blockIdx.x * HID + t] = p;
    }
}

// Kernel 2: reduce per-block partials -> pooled[128] -> MLP -> scalar.
__global__ __launch_bounds__(256) void reduce_mlp_kernel(
    const float* __restrict__ partial,
    const float* __restrict__ w2, const float* __restrict__ b2,
    const float* __restrict__ w3, const float* __restrict__ b3,
    float* __restrict__ out)
{
    __shared__ float s_tmp[256];
    __shared__ float s_pool[HID];
    __shared__ float s_ws[2];
    const int t = threadIdx.x;
    const int f = t & 127, sl = t >> 7;

    float acc = 0.f;
    for (int r = sl; r < NBLK; r += 2) acc += partial[r * HID + f];
    s_tmp[t] = acc;
    __syncthreads();
    if (t < HID) s_pool[t] = s_tmp[t] + s_tmp[t + 128];
    __syncthreads();

    if (t < HID) {
        float y = b2[t];
        for (int k = 0; k < HID; ++k) y = fmaf(s_pool[k], w2[k * HID + t], y);
        y = fmaxf(y, 0.f);
        float v = y * w3[t];
#pragma unroll
        for (int m = 1; m < 64; m <<= 1) v += __shfl_xor(v, m);
        if ((t & 63) == 0) s_ws[t >> 6] = v;
    }
    __syncthreads();
    if (t == 0) out[0] = s_ws[0] + s_ws[1] + b3[0];
}

extern "C" void kernel_launch(void* const* d_in, const int* in_sizes, int n_in,
                              void* d_out, int out_size, void* d_ws, size_t ws_size,
                              hipStream_t stream) {
    const float* state  = (const float*)d_in[0];
    const float* action = (const float*)d_in[1];
    const float* conv_w = (const float*)d_in[2];
    const float* conv_b = (const float*)d_in[3];
    const float* ln_g   = (const float*)d_in[4];
    const float* ln_b   = (const float*)d_in[5];
    const float* w2     = (const float*)d_in[6];
    const float* b2     = (const float*)d_in[7];
    const float* w3     = (const float*)d_in[8];
    const float* b3     = (const float*)d_in[9];
    // d_in[10]=src, d_in[11]=dst: fixed bidirectional chain, closed-form stencil.
    float* partial = (float*)d_ws;               // NBLK*HID*4 = 320 KB scratch

    gcn_ln_pool_kernel<<<NBLK, 256, 0, stream>>>(state, action, conv_w, conv_b,
                                                 ln_g, ln_b, partial);
    reduce_mlp_kernel<<<1, 256, 0, stream>>>(partial, w2, b2, w3, b3, (float*)d_out);
}

// Round 2
// 33.844 us; speedup vs baseline: 5.0879x; 5.0879x over previous
//
#include <hip/hip_runtime.h>
#include <math.h>

#define N_NODES 10000
#define BATCH   32
#define F_IN    5
#define HID     128
#define LN_EPS  1e-5f
#define CHUNK   500
#define NB_PER_BATCH (N_NODES / CHUNK)   // 20
#define NBLK (BATCH * NB_PER_BATCH)      // 640
#define GROUPS ((CHUNK + 7) / 8)         // 63 (last group: 4 valid nodes)

// Kernel 1: fused stencil-GCN + ReLU + LayerNorm + pooled partials.
// Layout: 8 lanes per node (feature-slot s = lane&7 owns features s*16..s*16+15),
// node-in-group = lane>>3 -> 8 nodes per wave-visit. LN reduce = 3-level butterfly.
// Pooled trick: sum_n (v-mean)*r = S1 - S2 with S1[f]=sum v[f]*r, S2=sum mean*r;
// ln_g/ln_b applied in kernel 2. Invalid nodes masked by r=0.
__global__ __launch_bounds__(256) void gcn_ln_pool_kernel(
    const float* __restrict__ state, const float* __restrict__ action,
    const float* __restrict__ conv_w, const float* __restrict__ conv_b,
    float* __restrict__ partial)
{
    __shared__ float s_sa[(CHUNK + 2) * F_IN];   // nodes [n0-1, n0+CHUNK]
    __shared__ float s_red[4][HID];

    const int b     = blockIdx.x / NB_PER_BATCH;
    const int chunk = blockIdx.x % NB_PER_BATCH;
    const int n0    = chunk * CHUNK;
    const int t     = threadIdx.x;

    // Stage sa = flat [state_row | action_row] slice, coalesced.
    const int base = (n0 - 1) * F_IN;
    for (int e = t; e < (CHUNK + 2) * F_IN; e += 256) {
        int g = base + e;
        float v = 0.f;
        if (g >= 0 && g < N_NODES * F_IN) {
            v = (g < N_NODES * 4) ? state[b * (N_NODES * 4) + g]
                                  : action[b * N_NODES + (g - N_NODES * 4)];
        }
        s_sa[e] = v;
    }

    const int wave = t >> 6;
    const int lane = t & 63;
    const int s    = lane & 7;        // feature slot: features s*16 .. s*16+15
    const int ng   = lane >> 3;       // node index within 8-node group

    // Loop-invariant params in registers (80 + 16 regs).
    float w[F_IN][16], cb[16];
#pragma unroll
    for (int j = 0; j < 16; ++j) {
        cb[j] = conv_b[s * 16 + j];
#pragma unroll
        for (int k = 0; k < F_IN; ++k) w[k][j] = conv_w[k * HID + s * 16 + j];
    }

    __syncthreads();

    float acc[16];
#pragma unroll
    for (int j = 0; j < 16; ++j) acc[j] = 0.f;
    float accS = 0.f;                 // sum of mean*r over this lane's nodes

    for (int g = wave; g < GROUPS; g += 4) {
        const int local = g * 8 + ng;
        const bool valid = local < CHUNK;
        const int loc = valid ? local : CHUNK - 1;   // clamp LDS index
        const int n = n0 + local;

        // GCN stencil weights (deg: 2 at chain ends, 3 interior).
        const float degC = (n == 0 || n == N_NODES - 1) ? 2.f : 3.f;
        const float wC = 1.f / degC;
        const float wL = (n > 0) ? rsqrtf(((n == 1) ? 2.f : 3.f) * degC) : 0.f;
        const float wR = (n < N_NODES - 1) ? rsqrtf(((n == N_NODES - 2) ? 2.f : 3.f) * degC) : 0.f;

        const int li = (loc + 1) * F_IN;
        float sagg[F_IN];
#pragma unroll
        for (int k = 0; k < F_IN; ++k)
            sagg[k] = wL * s_sa[li - F_IN + k] + wC * s_sa[li + k] + wR * s_sa[li + F_IN + k];

        float v[16], sum = 0.f, sq = 0.f;
#pragma unroll
        for (int j = 0; j < 16; ++j) {
            float x = cb[j];
#pragma unroll
            for (int k = 0; k < F_IN; ++k) x = fmaf(sagg[k], w[k][j], x);
            x = fmaxf(x, 0.f);
            v[j] = x;
            sum += x;
            sq = fmaf(x, x, sq);
        }
        // 3-level butterfly over the 8 lanes sharing this node (masks 1,2,4).
#pragma unroll
        for (int m = 1; m < 8; m <<= 1) {
            sum += __shfl_xor(sum, m);
            sq  += __shfl_xor(sq, m);
        }
        const float mean = sum * (1.f / 128.f);
        const float var  = sq * (1.f / 128.f) - mean * mean;
        float r = rsqrtf(var + LN_EPS);
        r = valid ? r : 0.f;          // mask: invalid nodes contribute exactly 0

#pragma unroll
        for (int j = 0; j < 16; ++j) acc[j] = fmaf(v[j], r, acc[j]);
        accS = fmaf(mean, r, accS);
    }

    // Reduce across the 8 node-groups (masks 8,16,32): same s -> same features.
#pragma unroll
    for (int m = 8; m < 64; m <<= 1) {
#pragma unroll
        for (int j = 0; j < 16; ++j) acc[j] += __shfl_xor(acc[j], m);
        accS += __shfl_xor(accS, m);
    }
    if (lane < 8) {
#pragma unroll
        for (int j = 0; j < 16; ++j) s_red[wave][lane * 16 + j] = acc[j] - accS;
    }
    __syncthreads();
    if (t < HID)
        partial[blockIdx.x * HID + t] =
            s_red[0][t] + s_red[1][t] + s_red[2][t] + s_red[3][t];
}

// Kernel 2: reduce 640 partials -> apply ln_g/ln_b -> MLP -> scalar.
__global__ __launch_bounds__(1024) void reduce_mlp_kernel(
    const float* __restrict__ partial,
    const float* __restrict__ ln_g, const float* __restrict__ ln_b,
    const float* __restrict__ w2, const float* __restrict__ b2,
    const float* __restrict__ w3, const float* __restrict__ b3,
    float* __restrict__ out)
{
    __shared__ float s_red[8][HID];
    __shared__ float s_pool[HID];
    __shared__ float s_ws[2];
    const int t = threadIdx.x;
    const int f = t & 127, sl = t >> 7;   // 8 slices

    float acc = 0.f;
#pragma unroll 8
    for (int r = sl; r < NBLK; r += 8) acc += partial[r * HID + f];
    s_red[sl][f] = acc;
    __syncthreads();

    if (t < HID) {
        float p = 0.f;
#pragma unroll
        for (int i = 0; i < 8; ++i) p += s_red[i][t];
        // pooled xn sum = ln_g*(S1-S2) + (B*N)*ln_b
        s_pool[t] = fmaf(ln_g[t], p, (float)(BATCH * N_NODES) * ln_b[t]);
    }
    __syncthreads();

    // y = relu(pool @ w2 + b2), k split 8 ways.
    float yp = 0.f;
    const int k0 = sl * 16;
#pragma unroll
    for (int k = 0; k < 16; ++k) yp = fmaf(s_pool[k0 + k], w2[(k0 + k) * HID + f], yp);
    __syncthreads();                  // s_red reuse hazard
    s_red[sl][f] = yp;
    __syncthreads();

    if (t < HID) {
        float y = b2[t];
#pragma unroll
        for (int i = 0; i < 8; ++i) y += s_red[i][t];
        y = fmaxf(y, 0.f);
        float v = y * w3[t];
#pragma unroll
        for (int m = 1; m < 64; m <<= 1) v += __shfl_xor(v, m);
        if ((t & 63) == 0) s_ws[t >> 6] = v;
    }
    __syncthreads();
    if (t == 0) out[0] = s_ws[0] + s_ws[1] + b3[0];
}

extern "C" void kernel_launch(void* const* d_in, const int* in_sizes, int n_in,
                              void* d_out, int out_size, void* d_ws, size_t ws_size,
                              hipStream_t stream) {
    const float* state  = (const float*)d_in[0];
    const float* action = (const float*)d_in[1];
    const float* conv_w = (const float*)d_in[2];
    const float* conv_b = (const float*)d_in[3];
    const float* ln_g   = (const float*)d_in[4];
    const float* ln_b   = (const float*)d_in[5];
    const float* w2     = (const float*)d_in[6];
    const float* b2     = (const float*)d_in[7];
    const float* w3     = (const float*)d_in[8];
    const float* b3     = (const float*)d_in[9];
    // d_in[10]=src, d_in[11]=dst: fixed bidirectional chain -> closed-form stencil.
    float* partial = (float*)d_ws;    // NBLK*HID*4 = 320 KB scratch

    gcn_ln_pool_kernel<<<NBLK, 256, 0, stream>>>(state, action, conv_w, conv_b, partial);
    reduce_mlp_kernel<<<1, 1024, 0, stream>>>(partial, ln_g, ln_b, w2, b2, w3, b3,
                                              (float*)d_out);
}

// Round 5
// 28.701 us; speedup vs baseline: 5.9996x; 1.1792x over previous
//
#include <hip/hip_runtime.h>
#include <math.h>

#define N_NODES 10000
#define BATCH   32
#define F_IN    5
#define HID     128
#define LN_EPS  1e-5f
#define CHUNK   500
#define NB_PER_BATCH 20                   // N_NODES / CHUNK
#define NBLK (BATCH * NB_PER_BATCH)       // 640
#define CONCAT_N (N_NODES * F_IN)         // 50000
#define STATE_N  (N_NODES * 4)            // 40000
#define STAGE_F4 635                      // 2540 floats: nodes [n0-4, n0+504)

// Kernel 1: fused stencil-GCN + ReLU + LayerNorm + pooled partials.
// Phase 1 (per 64-node supergroup): lane L aggregates the 5-dim stencil input
// for node base+L (15 conflict-free ds_reads per 64 nodes).
// Phase 2: 8 sub-batches of 8 nodes; 8 lanes/node (slot s = lane&7 owns
// features s*16..s*16+15); sagg redistributed by 5 __shfl; LN = 3-level butterfly.
// Pooled trick: sum_n (v-mean)*r = S1 - S2; ln_g/ln_b applied in kernel 2.
__global__ __launch_bounds__(256) void gcn_ln_pool_kernel(
    const float* __restrict__ state, const float* __restrict__ action,
    const float* __restrict__ conv_w, const float* __restrict__ conv_b,
    float* __restrict__ partial)
{
    __shared__ float s_sa[2560];          // nodes [n0-4, n0+504), 5 floats each
    __shared__ float s_red[4][HID];

    const int b     = blockIdx.x / NB_PER_BATCH;
    const int chunk = blockIdx.x % NB_PER_BATCH;
    const int n0    = chunk * CHUNK;
    const int t     = threadIdx.x;

    // Stage sa slice as float4 (base (n0-4)*5 is 16B-aligned; concat boundary
    // at element 40000 is float4-aligned, so no vector straddles state/action).
    const int e0 = (n0 - 4) * F_IN;
    const float4* stv = (const float4*)(state  + b * STATE_N);
    const float4* acv = (const float4*)(action + b * N_NODES);
    for (int i = t; i < STAGE_F4; i += 256) {
        const int e = e0 + i * 4;
        float4 v = make_float4(0.f, 0.f, 0.f, 0.f);
        if (e >= 0 && e < CONCAT_N)
            v = (e < STATE_N) ? stv[e >> 2] : acv[(e - STATE_N) >> 2];
        ((float4*)s_sa)[i] = v;
    }

    const int wave = t >> 6;
    const int lane = t & 63;
    const int s    = lane & 7;            // feature slot
    const int ng   = lane >> 3;           // node within sub-batch

    float w[F_IN][16], cb[16];
#pragma unroll
    for (int j = 0; j < 16; ++j) {
        cb[j] = conv_b[s * 16 + j];
#pragma unroll
        for (int k = 0; k < F_IN; ++k) w[k][j] = conv_w[k * HID + s * 16 + j];
    }

    __syncthreads();

    float acc[16];
#pragma unroll
    for (int j = 0; j < 16; ++j) acc[j] = 0.f;
    float accS = 0.f;

    const float R33 = 1.f / 3.f;
    const float R23 = 0.40824829046386301637f;   // rsqrt(2*3)

    for (int sgi = wave; sgi < 8; sgi += 4) {
        // ---- phase 1: stencil-aggregate for node n0 + sgi*64 + lane
        const int loc1 = min(sgi * 64 + lane, CHUNK - 1);   // clamp (finite garbage ok)
        const int n    = n0 + loc1;
        // deg = 2 at chain ends, 3 interior -> only nodes 0,1,9998,9999 special.
        const float wC = (n == 0 || n == N_NODES - 1) ? 0.5f : R33;
        const float wL = (n == 0) ? 0.f : ((n == 1 || n == N_NODES - 1) ? R23 : R33);
        const float wR = (n == N_NODES - 1) ? 0.f : ((n == N_NODES - 2 || n == 0) ? R23 : R33);
        const int li = (loc1 + 4) * F_IN;
        float sga[F_IN];
#pragma unroll
        for (int k = 0; k < F_IN; ++k)
            sga[k] = fmaf(s_sa[li - F_IN + k], wL,
                     fmaf(s_sa[li + k],        wC,
                          s_sa[li + F_IN + k] * wR));

        // ---- phase 2: 8 sub-batches of 8 nodes
        for (int sb = 0; sb < 8; ++sb) {
            const int src   = sb * 8 + ng;
            const int local = sgi * 64 + src;
            const bool valid = local < CHUNK;
            const float a0 = __shfl(sga[0], src);
            const float a1 = __shfl(sga[1], src);
            const float a2 = __shfl(sga[2], src);
            const float a3 = __shfl(sga[3], src);
            const float a4 = __shfl(sga[4], src);

            float v[16], sum = 0.f, sq = 0.f;
#pragma unroll
            for (int j = 0; j < 16; ++j) {
                float x = cb[j];
                x = fmaf(a0, w[0][j], x);
                x = fmaf(a1, w[1][j], x);
                x = fmaf(a2, w[2][j], x);
                x = fmaf(a3, w[3][j], x);
                x = fmaf(a4, w[4][j], x);
                x = fmaxf(x, 0.f);
                v[j] = x;
                sum += x;
                sq = fmaf(x, x, sq);
            }
#pragma unroll
            for (int m = 1; m < 8; m <<= 1) {
                sum += __shfl_xor(sum, m);
                sq  += __shfl_xor(sq, m);
            }
            const float mean = sum * (1.f / 128.f);
            const float var  = sq * (1.f / 128.f) - mean * mean;
            float r = rsqrtf(var + LN_EPS);
            r = valid ? r : 0.f;          // invalid nodes contribute exactly 0
#pragma unroll
            for (int j = 0; j < 16; ++j) acc[j] = fmaf(v[j], r, acc[j]);
            accS = fmaf(mean, r, accS);
        }
    }

    // Reduce across the 8 node-groups (same feature slot s).
#pragma unroll
    for (int m = 8; m < 64; m <<= 1) {
#pragma unroll
        for (int j = 0; j < 16; ++j) acc[j] += __shfl_xor(acc[j], m);
        accS += __shfl_xor(accS, m);
    }
    if (lane < 8) {
#pragma unroll
        for (int j = 0; j < 16; ++j) s_red[wave][lane * 16 + j] = acc[j] - accS;
    }
    __syncthreads();
    if (t < HID)
        partial[blockIdx.x * HID + t] =
            s_red[0][t] + s_red[1][t] + s_red[2][t] + s_red[3][t];
}

// Kernel 2: reduce 640 partials -> apply ln_g/ln_b -> MLP -> scalar.
__global__ __launch_bounds__(1024) void reduce_mlp_kernel(
    const float* __restrict__ partial,
    const float* __restrict__ ln_g, const float* __restrict__ ln_b,
    const float* __restrict__ w2, const float* __restrict__ b2,
    const float* __restrict__ w3, const float* __restrict__ b3,
    float* __restrict__ out)
{
    __shared__ float s_red[8][HID];
    __shared__ float s_pool[HID];
    __shared__ float s_ws[2];
    const int t = threadIdx.x;
    const int f = t & 127, sl = t >> 7;   // 8 slices

    float acc = 0.f;
#pragma unroll 8
    for (int r = sl; r < NBLK; r += 8) acc += partial[r * HID + f];
    s_red[sl][f] = acc;
    __syncthreads();

    if (t < HID) {
        float p = 0.f;
#pragma unroll
        for (int i = 0; i < 8; ++i) p += s_red[i][t];
        // pooled xn sum = ln_g*(S1-S2) + (B*N)*ln_b
        s_pool[t] = fmaf(ln_g[t], p, (float)(BATCH * N_NODES) * ln_b[t]);
    }
    __syncthreads();

    // y = relu(pool @ w2 + b2), k split 8 ways.
    float yp = 0.f;
    const int k0 = sl * 16;
#pragma unroll
    for (int k = 0; k < 16; ++k) yp = fmaf(s_pool[k0 + k], w2[(k0 + k) * HID + f], yp);
    __syncthreads();                      // s_red reuse hazard
    s_red[sl][f] = yp;
    __syncthreads();

    if (t < HID) {
        float y = b2[t];
#pragma unroll
        for (int i = 0; i < 8; ++i) y += s_red[i][t];
        y = fmaxf(y, 0.f);
        float v = y * w3[t];
#pragma unroll
        for (int m = 1; m < 64; m <<= 1) v += __shfl_xor(v, m);
        if ((t & 63) == 0) s_ws[t >> 6] = v;
    }
    __syncthreads();
    if (t == 0) out[0] = s_ws[0] + s_ws[1] + b3[0];
}

extern "C" void kernel_launch(void* const* d_in, const int* in_sizes, int n_in,
                              void* d_out, int out_size, void* d_ws, size_t ws_size,
                              hipStream_t stream) {
    const float* state  = (const float*)d_in[0];
    const float* action = (const float*)d_in[1];
    const float* conv_w = (const float*)d_in[2];
    const float* conv_b = (const float*)d_in[3];
    const float* ln_g   = (const float*)d_in[4];
    const float* ln_b   = (const float*)d_in[5];
    const float* w2     = (const float*)d_in[6];
    const float* b2     = (const float*)d_in[7];
    const float* w3     = (const float*)d_in[8];
    const float* b3     = (const float*)d_in[9];
    // d_in[10]=src, d_in[11]=dst: fixed bidirectional chain -> closed-form stencil.
    float* partial = (float*)d_ws;        // NBLK*HID*4 = 320 KB scratch

    gcn_ln_pool_kernel<<<NBLK, 256, 0, stream>>>(state, action, conv_w, conv_b, partial);
    reduce_mlp_kernel<<<1, 1024, 0, stream>>>(partial, ln_g, ln_b, w2, b2, w3, b3,
                                              (float*)d_out);
}